// Round 5
// baseline (241.759 us; speedup 1.0000x reference)
//
#include <hip/hip_runtime.h>

// CtaPostAttnMixer: y = (I + 0.1*Lap)^4 x along l, fixed boundaries.
// One 9-tap conv (interior) + analytic boundary rows.
// x: (B=4, L=8192, D=1024) f32, D contiguous.
//
// R3/R4 lesson: per-thread windows -> compiler serializes loads (VGPR 48 cap
// heuristic) and 3x cache-level read amplification -> ~3.3 TB/s effective.
// R5: LDS-tiled. Block = 32 l-rows x 64 f4-cols, stages (32+8) rows x 1KB
// into 40KB LDS via async global_load_lds (width 16), 4 blocks/CU, then each
// thread computes 8 outputs from a 16-row LDS window. Amplification 1.25x.

namespace {

constexpr int Lr    = 8192;         // sequence length
constexpr int Dq    = 1024 / 4;     // float4 columns total = 256
constexpr int SW    = 64;           // stripe width in float4 cols
constexpr int NS    = Dq / SW;      // 4 column stripes
constexpr int Bn    = 4;            // batch
constexpr int TL    = 32;           // l-rows per tile
constexpr int LDSR  = TL + 8;       // staged rows = 40
constexpr int TILES = Lr / TL;      // 256

// 9-tap weights of (I + 0.1*Lap)^4  ([.1,.8,.1] convolved 4x)
constexpr float WK0 = 0.4870f;
constexpr float WK1 = 0.2144f;
constexpr float WK2 = 0.0388f;
constexpr float WK3 = 0.0032f;
constexpr float WK4 = 0.0001f;

typedef float nfloat4 __attribute__((ext_vector_type(4)));

__device__ __forceinline__ float4 f4_add(float4 a, float4 b) {
    return make_float4(a.x + b.x, a.y + b.y, a.z + b.z, a.w + b.w);
}
__device__ __forceinline__ float4 f4_mul(float s, float4 a) {
    return make_float4(s * a.x, s * a.y, s * a.z, s * a.w);
}
__device__ __forceinline__ float4 f4_fma(float s, float4 a, float4 c) {
    return make_float4(fmaf(s, a.x, c.x), fmaf(s, a.y, c.y),
                       fmaf(s, a.z, c.z), fmaf(s, a.w, c.w));
}
__device__ __forceinline__ void f4_store_nt(float4* p, float4 v) {
    nfloat4 nv;
    nv.x = v.x; nv.y = v.y; nv.z = v.z; nv.w = v.w;
    __builtin_nontemporal_store(nv, (nfloat4*)p);
}

#if defined(__has_builtin) && __has_builtin(__builtin_amdgcn_global_load_lds)
#define HAVE_GLL 1
#else
#define HAVE_GLL 0
#endif

__global__ __launch_bounds__(256, 4)   // VGPR cap 128; LDS gives 4 blocks/CU
void mixer4_kernel(const float4* __restrict__ x, float4* __restrict__ y) {
    __shared__ float4 sm[LDSR * SW];   // 40 rows x 64 f4 = 40 KB

    const int t    = threadIdx.x;
    const int lane = t & 63;
    const int wav  = t >> 6;           // 0..3
    const int tile = blockIdx.x;       // l-tile 0..255
    const int cs   = blockIdx.y;       // column stripe 0..3
    const int b    = blockIdx.z;       // batch 0..3
    const int l0   = tile * TL;

    const float4* __restrict__ xb = x + (size_t)b * Lr * Dq + cs * SW;
    float4* __restrict__       yb = y + (size_t)b * Lr * Dq + cs * SW;

    // ---- stage LDSR=40 rows; wave w stages rows w*10 .. w*10+9 ----
    // LDS row r  <-  x[clamp(l0 - 4 + r)], one 1KB contiguous row per inst.
#pragma unroll
    for (int i = 0; i < LDSR / 4; ++i) {            // 10 per wave
        int r  = wav * (LDSR / 4) + i;
        int gl = l0 - 4 + r;
        gl = gl < 0 ? 0 : gl;
        gl = gl > Lr - 1 ? Lr - 1 : gl;
        const float4* src = xb + (size_t)gl * Dq + lane;  // per-lane 16B
        float4*       dst = &sm[r * SW];                  // wave-uniform base
#if HAVE_GLL
        __builtin_amdgcn_global_load_lds(
            (const __attribute__((address_space(1))) void*)src,
            (__attribute__((address_space(3))) void*)dst, 16, 0, 0);
#else
        sm[r * SW + lane] = *src;
#endif
    }
    __syncthreads();   // drains vmcnt -> LDS valid

    // ---- compute: thread -> col c=lane, rows r0..r0+7 of the tile ----
    const int c  = lane;
    const int r0 = wav * 8;

    float4 w[16];      // LDS window rows r0..r0+15  (w[i] = x[l0-4+r0+i])
#pragma unroll
    for (int i = 0; i < 16; ++i) w[i] = sm[(r0 + i) * SW + c];

    const bool first = (tile == 0);
    const bool last  = (tile == TILES - 1);

    if (!(first && wav == 0) && !(last && wav == 3)) {
        // interior: 8 outputs, taps w[j..j+8], center w[j+4]
#pragma unroll
        for (int j = 0; j < 8; ++j) {
            float4 acc = f4_mul(WK0, w[j + 4]);
            acc = f4_fma(WK1, f4_add(w[j + 3], w[j + 5]), acc);
            acc = f4_fma(WK2, f4_add(w[j + 2], w[j + 6]), acc);
            acc = f4_fma(WK3, f4_add(w[j + 1], w[j + 7]), acc);
            acc = f4_fma(WK4, f4_add(w[j + 0], w[j + 8]), acc);
            f4_store_nt(&yb[(size_t)(l0 + r0 + j) * Dq + c], acc);
        }
    } else if (first && wav == 0) {
        // tile 0, wave 0: rows 0..3 special, 4..7 normal. w[4+i] = x[i].
        f4_store_nt(&yb[0 * Dq + c], w[4]);                       // l=0 copy
        {   // l=1
            float4 o = f4_mul(0.2986f, w[4]);
            o = f4_fma(0.4482f, w[5], o);
            o = f4_fma(0.2112f, w[6], o);
            o = f4_fma(0.0387f, w[7], o);
            o = f4_fma(0.0032f, w[8], o);
            o = f4_fma(0.0001f, w[9], o);
            f4_store_nt(&yb[(size_t)1 * Dq + c], o);
        }
        {   // l=2
            float4 o = f4_mul(0.0454f, w[4]);
            o = f4_fma(0.2112f, w[5], o);
            o = f4_fma(0.4869f, w[6], o);
            o = f4_fma(0.2144f, w[7], o);
            o = f4_fma(0.0388f, w[8], o);
            o = f4_fma(0.0032f, w[9], o);
            o = f4_fma(0.0001f, w[10], o);
            f4_store_nt(&yb[(size_t)2 * Dq + c], o);
        }
        {   // l=3
            float4 o = f4_mul(0.0034f, w[4]);
            o = f4_fma(0.0387f, w[5], o);
            o = f4_fma(0.2144f, w[6], o);
            o = f4_fma(0.4870f, w[7], o);
            o = f4_fma(0.2144f, w[8], o);
            o = f4_fma(0.0388f, w[9], o);
            o = f4_fma(0.0032f, w[10], o);
            o = f4_fma(0.0001f, w[11], o);
            f4_store_nt(&yb[(size_t)3 * Dq + c], o);
        }
#pragma unroll
        for (int j = 4; j < 8; ++j) {   // l=4..7 normal
            float4 acc = f4_mul(WK0, w[j + 4]);
            acc = f4_fma(WK1, f4_add(w[j + 3], w[j + 5]), acc);
            acc = f4_fma(WK2, f4_add(w[j + 2], w[j + 6]), acc);
            acc = f4_fma(WK3, f4_add(w[j + 1], w[j + 7]), acc);
            acc = f4_fma(WK4, f4_add(w[j + 0], w[j + 8]), acc);
            f4_store_nt(&yb[(size_t)j * Dq + c], acc);
        }
    } else {
        // last tile, wave 3: r0=24, w[i] = x[Lr-12+i] (i<=11 unclamped).
        // x[Lr-1-p] = w[11-p]. Rows j=0..3 (g=Lr-8..Lr-5) normal; 4..7 special.
#pragma unroll
        for (int j = 0; j < 4; ++j) {
            float4 acc = f4_mul(WK0, w[j + 4]);
            acc = f4_fma(WK1, f4_add(w[j + 3], w[j + 5]), acc);
            acc = f4_fma(WK2, f4_add(w[j + 2], w[j + 6]), acc);
            acc = f4_fma(WK3, f4_add(w[j + 1], w[j + 7]), acc);
            acc = f4_fma(WK4, f4_add(w[j + 0], w[j + 8]), acc);
            f4_store_nt(&yb[(size_t)(l0 + 24 + j) * Dq + c], acc);
        }
        f4_store_nt(&yb[(size_t)(Lr - 1) * Dq + c], w[11]);       // copy
        {   // l = Lr-2 (mirrored row1)
            float4 o = f4_mul(0.2986f, w[11]);
            o = f4_fma(0.4482f, w[10], o);
            o = f4_fma(0.2112f, w[9], o);
            o = f4_fma(0.0387f, w[8], o);
            o = f4_fma(0.0032f, w[7], o);
            o = f4_fma(0.0001f, w[6], o);
            f4_store_nt(&yb[(size_t)(Lr - 2) * Dq + c], o);
        }
        {   // l = Lr-3 (mirrored row2)
            float4 o = f4_mul(0.0454f, w[11]);
            o = f4_fma(0.2112f, w[10], o);
            o = f4_fma(0.4869f, w[9], o);
            o = f4_fma(0.2144f, w[8], o);
            o = f4_fma(0.0388f, w[7], o);
            o = f4_fma(0.0032f, w[6], o);
            o = f4_fma(0.0001f, w[5], o);
            f4_store_nt(&yb[(size_t)(Lr - 3) * Dq + c], o);
        }
        {   // l = Lr-4 (mirrored row3)
            float4 o = f4_mul(0.0034f, w[11]);
            o = f4_fma(0.0387f, w[10], o);
            o = f4_fma(0.2144f, w[9], o);
            o = f4_fma(0.4870f, w[8], o);
            o = f4_fma(0.2144f, w[7], o);
            o = f4_fma(0.0388f, w[6], o);
            o = f4_fma(0.0032f, w[5], o);
            o = f4_fma(0.0001f, w[4], o);
            f4_store_nt(&yb[(size_t)(Lr - 4) * Dq + c], o);
        }
    }
}

}  // namespace

extern "C" void kernel_launch(void* const* d_in, const int* in_sizes, int n_in,
                              void* d_out, int out_size, void* d_ws, size_t ws_size,
                              hipStream_t stream) {
    const float4* x = (const float4*)d_in[0];
    float4*       y = (float4*)d_out;

    dim3 grid(TILES, NS, Bn);   // 256 x 4 x 4 = 4096 blocks
    dim3 block(256);
    hipLaunchKernelGGL(mixer4_kernel, grid, block, 0, stream, x, y);
}